// Round 1
// baseline (2378.227 us; speedup 1.0000x reference)
//
#include <hip/hip_runtime.h>

#define NN 100000
#define NE 3200000
#define NG 256
#define H 32

// Monotone bijection float -> u32 (order-preserving), so u32 max == float max.
__device__ __forceinline__ unsigned encf(float f) {
    unsigned u = __float_as_uint(f);
    return (u & 0x80000000u) ? ~u : (u | 0x80000000u);
}
__device__ __forceinline__ float decf(unsigned u) {
    return __uint_as_float((u & 0x80000000u) ? (u & 0x7fffffffu) : ~u);
}

// Init aggregation buffer to enc(0.0f) = 0x80000000 (folds neginf->0 fill AND relu).
__global__ __launch_bounds__(256) void k_init(unsigned* __restrict__ agg,
                                              unsigned* __restrict__ g) {
    int i = blockIdx.x * 256 + threadIdx.x;   // grid covers exactly NN*H
    agg[i] = 0x80000000u;
    if (i < NG * H) g[i] = 0x80000000u;
}

__global__ __launch_bounds__(256) void k_reset(unsigned* __restrict__ agg) {
    int i = blockIdx.x * 256 + threadIdx.x;
    agg[i] = 0x80000000u;
}

// Layer-1 per-node precompute:
//   F[n][k] = sum_i pos[n][i] * W1a[3+i][k]          (pos-diff part)
//   E[n][k] = b1a[k] + sum_i pos[n][i]*W1a[i][k] + F[n][k]
// so per-edge t = relu(E[src] - F[dst]).
__global__ __launch_bounds__(256) void k_pre1(const float* __restrict__ pos,
                                              const float* __restrict__ W1a,
                                              const float* __restrict__ b1a,
                                              float* __restrict__ E,
                                              float* __restrict__ F) {
    int n = blockIdx.x * 256 + threadIdx.x;
    if (n >= NN) return;
    float p0 = pos[3 * n], p1 = pos[3 * n + 1], p2 = pos[3 * n + 2];
    float ev[H], fv[H];
#pragma unroll
    for (int k = 0; k < H; k++) {
        float f = p0 * W1a[3 * H + k] + p1 * W1a[4 * H + k] + p2 * W1a[5 * H + k];
        float e = b1a[k] + p0 * W1a[k] + p1 * W1a[H + k] + p2 * W1a[2 * H + k] + f;
        fv[k] = f;
        ev[k] = e;
    }
    float4* E4 = (float4*)(E + (size_t)n * H);
    float4* F4 = (float4*)(F + (size_t)n * H);
#pragma unroll
    for (int r = 0; r < 8; r++) {
        E4[r] = make_float4(ev[4 * r], ev[4 * r + 1], ev[4 * r + 2], ev[4 * r + 3]);
        F4[r] = make_float4(fv[4 * r], fv[4 * r + 1], fv[4 * r + 2], fv[4 * r + 3]);
    }
}

// Layer-2 per-node precompute: h1 = dec(agg1) (>=0 already; relu folded by init),
//   F[n][k] = sum_i pos[n][i] * W2a[(32+i)][k]
//   E[n][k] = b2a[k] + F[n][k] + sum_j h1[n][j]*W2a[j][k]
__global__ __launch_bounds__(256) void k_pre2(const float* __restrict__ pos,
                                              const unsigned* __restrict__ agg,
                                              const float* __restrict__ W2a,
                                              const float* __restrict__ b2a,
                                              float* __restrict__ E,
                                              float* __restrict__ F) {
    int n = blockIdx.x * 256 + threadIdx.x;
    if (n >= NN) return;
    float h[H];
    const uint4* A4 = (const uint4*)(agg + (size_t)n * H);
#pragma unroll
    for (int r = 0; r < 8; r++) {
        uint4 u = A4[r];
        h[4 * r + 0] = decf(u.x);
        h[4 * r + 1] = decf(u.y);
        h[4 * r + 2] = decf(u.z);
        h[4 * r + 3] = decf(u.w);
    }
    float p0 = pos[3 * n], p1 = pos[3 * n + 1], p2 = pos[3 * n + 2];
    float ev[H], fv[H];
#pragma unroll
    for (int k = 0; k < H; k++) {
        float f = p0 * W2a[32 * H + k] + p1 * W2a[33 * H + k] + p2 * W2a[34 * H + k];
        fv[k] = f;
        ev[k] = b2a[k] + f;
    }
#pragma unroll
    for (int j = 0; j < H; j++) {
        float hj = h[j];
#pragma unroll
        for (int k = 0; k < H; k++) ev[k] = fmaf(hj, W2a[j * H + k], ev[k]);
    }
    float4* E4 = (float4*)(E + (size_t)n * H);
    float4* F4 = (float4*)(F + (size_t)n * H);
#pragma unroll
    for (int r = 0; r < 8; r++) {
        E4[r] = make_float4(ev[4 * r], ev[4 * r + 1], ev[4 * r + 2], ev[4 * r + 3]);
        F4[r] = make_float4(fv[4 * r], fv[4 * r + 1], fv[4 * r + 2], fv[4 * r + 3]);
    }
}

// Shared edge kernel for both layers:
//   t = relu(E[src]-F[dst]); msg = t @ W + b; agg[dst] = max(agg[dst], msg)
// Test-before-atomic is safe: agg values only grow; a stale read is only ever
// too LOW, causing at worst a redundant atomic, never a missed update.
__global__ __launch_bounds__(256) void k_edge(const int* __restrict__ src,
                                              const int* __restrict__ dst,
                                              const float* __restrict__ E,
                                              const float* __restrict__ F,
                                              const float* __restrict__ W,
                                              const float* __restrict__ b,
                                              unsigned* __restrict__ agg) {
    int e = blockIdx.x * 256 + threadIdx.x;  // grid covers exactly NE
    int s = src[e], d = dst[e];
    const float4* E4 = (const float4*)(E + (size_t)s * H);
    const float4* F4 = (const float4*)(F + (size_t)d * H);
    float t[H];
#pragma unroll
    for (int r = 0; r < 8; r++) {
        float4 a = E4[r], c = F4[r];
        t[4 * r + 0] = fmaxf(a.x - c.x, 0.f);
        t[4 * r + 1] = fmaxf(a.y - c.y, 0.f);
        t[4 * r + 2] = fmaxf(a.z - c.z, 0.f);
        t[4 * r + 3] = fmaxf(a.w - c.w, 0.f);
    }
    float m[H];
#pragma unroll
    for (int k = 0; k < H; k++) m[k] = b[k];
#pragma unroll
    for (int j = 0; j < H; j++) {
        float tj = t[j];
#pragma unroll
        for (int k = 0; k < H; k++) m[k] = fmaf(tj, W[j * H + k], m[k]);
    }
    unsigned* ag = agg + (size_t)d * H;
#pragma unroll
    for (int r = 0; r < 8; r++) {
        uint4 c = ((const uint4*)ag)[r];
        unsigned v0 = encf(m[4 * r + 0]);
        unsigned v1 = encf(m[4 * r + 1]);
        unsigned v2 = encf(m[4 * r + 2]);
        unsigned v3 = encf(m[4 * r + 3]);
        if (v0 > c.x) atomicMax(ag + 4 * r + 0, v0);
        if (v1 > c.y) atomicMax(ag + 4 * r + 1, v1);
        if (v2 > c.z) atomicMax(ag + 4 * r + 2, v2);
        if (v3 > c.w) atomicMax(ag + 4 * r + 3, v3);
    }
}

// Graph max-pool: values stay in encoded domain (monotone => max commutes).
__global__ __launch_bounds__(256) void k_pool(const unsigned* __restrict__ agg,
                                              const int* __restrict__ batch,
                                              unsigned* __restrict__ g) {
    int n = blockIdx.x * 256 + threadIdx.x;
    if (n >= NN) return;
    int bidx = batch[n];
    unsigned* gb = g + (size_t)bidx * H;
    const uint4* A4 = (const uint4*)(agg + (size_t)n * H);
#pragma unroll
    for (int r = 0; r < 8; r++) {
        uint4 v = A4[r];
        uint4 c = ((const uint4*)gb)[r];
        if (v.x > c.x) atomicMax(gb + 4 * r + 0, v.x);
        if (v.y > c.y) atomicMax(gb + 4 * r + 1, v.y);
        if (v.z > c.z) atomicMax(gb + 4 * r + 2, v.z);
        if (v.w > c.w) atomicMax(gb + 4 * r + 3, v.w);
    }
}

__global__ __launch_bounds__(256) void k_out(const unsigned* __restrict__ g,
                                             const float* __restrict__ Wout,
                                             const float* __restrict__ bout,
                                             float* __restrict__ out) {
    int bidx = threadIdx.x;  // one block of 256
    float acc = bout[0];
#pragma unroll
    for (int k = 0; k < H; k++) acc = fmaf(decf(g[bidx * H + k]), Wout[k], acc);
    out[bidx] = acc;
}

extern "C" void kernel_launch(void* const* d_in, const int* in_sizes, int n_in,
                              void* d_out, int out_size, void* d_ws, size_t ws_size,
                              hipStream_t stream) {
    const float* pos  = (const float*)d_in[0];
    const int* src    = (const int*)d_in[1];
    const int* dst    = src + NE;
    const int* batch  = (const int*)d_in[2];
    const float* W1a  = (const float*)d_in[3];
    const float* b1a  = (const float*)d_in[4];
    const float* W1b  = (const float*)d_in[5];
    const float* b1b  = (const float*)d_in[6];
    const float* W2a  = (const float*)d_in[7];
    const float* b2a  = (const float*)d_in[8];
    const float* W2b  = (const float*)d_in[9];
    const float* b2b  = (const float*)d_in[10];
    const float* Wout = (const float*)d_in[11];
    const float* bout = (const float*)d_in[12];
    float* out = (float*)d_out;

    const size_t SZ = (size_t)NN * H;  // elems per node-feature buffer
    unsigned* agg = (unsigned*)d_ws;                // reused for both layers
    float* E      = (float*)d_ws + SZ;
    float* F      = (float*)d_ws + 2 * SZ;
    unsigned* g   = (unsigned*)d_ws + 3 * SZ;       // total ~38.4 MB + 32 KB

    const int EDGE_BLOCKS = NE / 256;        // 12500, exact
    const int AGG_BLOCKS  = (NN * H) / 256;  // 12500, exact
    const int NODE_BLOCKS = (NN + 255) / 256;

    k_init<<<AGG_BLOCKS, 256, 0, stream>>>(agg, g);
    k_pre1<<<NODE_BLOCKS, 256, 0, stream>>>(pos, W1a, b1a, E, F);
    k_edge<<<EDGE_BLOCKS, 256, 0, stream>>>(src, dst, E, F, W1b, b1b, agg);
    k_pre2<<<NODE_BLOCKS, 256, 0, stream>>>(pos, agg, W2a, b2a, E, F);
    k_reset<<<AGG_BLOCKS, 256, 0, stream>>>(agg);
    k_edge<<<EDGE_BLOCKS, 256, 0, stream>>>(src, dst, E, F, W2b, b2b, agg);
    k_pool<<<NODE_BLOCKS, 256, 0, stream>>>(agg, batch, g);
    k_out<<<1, 256, 0, stream>>>(g, Wout, bout, out);
}